// Round 12
// baseline (400.886 us; speedup 1.0000x reference)
//
#include <hip/hip_runtime.h>
#include <hip/hip_bf16.h>

#define T_WIN 336
#define T_OUT 48
#define T_S   168
#define BM    128
#define CH    782
#define NPREP 302   // blocks 1..302: W1F(264) + W2F(36) + cs(2)

typedef __attribute__((ext_vector_type(8))) short short8;
typedef __attribute__((ext_vector_type(4))) float f32x4;

__device__ __forceinline__ short f2bf(float f) {
    union { float f; unsigned u; } v; v.f = f;
    unsigned r = v.u + 0x7FFFu + ((v.u >> 16) & 1u);
    return (short)(r >> 16);
}

template <int CTRL, int RMASK>
__device__ __forceinline__ float dppf(float v) {
    union { float f; int i; } in, out;
    in.f = v;
    out.i = __builtin_amdgcn_update_dpp(0, in.i, CTRL, RMASK, 0xf, true);
    return out.f;
}

__global__ void init_kernel(int* cnt) { cnt[0] = 0; cnt[1] = 0; }

// ================= mega kernel: scan (blk 0) || preps (1..302) || gemm || loss1 =================
// Producer-consumer streaming: scan publishes "levels valid through index v" via
// release-fence + device-scope atomicExch; consumers poll with atomic RMW + s_sleep
// backoff, then acquire-fence. gemm block n0 needs levels<=n0+463, w_all<=n0+631 (= v+168).
__global__ __launch_bounds__(256, 4) void mega_kernel(
    const float* __restrict__ x, const float* __restrict__ lvl_coef,
    const float* __restrict__ seas_coef, const float* __restrict__ seas_params,
    const float* __restrict__ W1, const float* __restrict__ W2,
    const float* __restrict__ b1, const float* __restrict__ b2,
    float* __restrict__ w_all, float* __restrict__ levels,
    short* __restrict__ W1F, short* __restrict__ W2F,
    float* __restrict__ cs, float* __restrict__ lpart,
    float* __restrict__ outp, float* __restrict__ lab,
    int* cnt, int T, int N, int NB)
{
    __shared__ float Lsf[512];
    __shared__ __align__(16) short Lbf0[512];
    __shared__ __align__(16) short Lbf1[512];
    __shared__ float llv[BM];
    __shared__ __align__(16) short hs[BM * 72];

    int blk = blockIdx.x;
    int tid = threadIdx.x;

    // ---------------- preps: blocks 1..302 ----------------
    if (blk >= 1 && blk <= NPREP) {
        if (blk >= 301) {                       // cs: colsum of W1
            int k = (blk - 301) * 256 + tid;
            if (k < T_WIN) {
                float s = 0.f;
                for (int j = 0; j < T_WIN; ++j) s += W1[j * T_WIN + k];
                cs[k] = s;
            }
        } else if (blk >= 265) {                // W2F: [f=(c*2+kt2)*3+ct2][lane][j]
            int d = (blk - 265) * 256 + tid;
            int j2 = d & 3, lane = (d >> 2) & 63, f = d >> 8;
            int ct2 = f % 3, rest = f / 3;
            int kt2 = rest & 1, c = rest >> 1;
            int k = c * 64 + kt2 * 32 + (lane >> 4) * 8 + 2 * j2;
            int o = ct2 * 16 + (lane & 15);
            unsigned short lo = 0, hi = 0;
            if (k     < T_WIN) lo = (unsigned short)f2bf(W2[k * T_OUT + o]);
            if (k + 1 < T_WIN) hi = (unsigned short)f2bf(W2[(k + 1) * T_OUT + o]);
            ((unsigned*)W2F)[d] = ((unsigned)hi << 16) | (unsigned)lo;
        } else {                                // W1F: [f=(c*11+kt)*4+ct][lane][j]
            int d = (blk - 1) * 256 + tid;
            int j2 = d & 3, lane = (d >> 2) & 63, f = d >> 8;
            int ct = f & 3, rest = f >> 2;
            int kt = rest % 11, c = rest / 11;
            int k = kt * 32 + (lane >> 4) * 8 + 2 * j2;
            int col = c * 64 + ct * 16 + (lane & 15);
            unsigned short lo = 0, hi = 0;
            if (col < T_WIN) {
                if (k     < T_WIN) lo = (unsigned short)f2bf(W1[k * T_WIN + col]);
                if (k + 1 < T_WIN) hi = (unsigned short)f2bf(W1[(k + 1) * T_WIN + col]);
            }
            ((unsigned*)W1F)[d] = ((unsigned)hi << 16) | (unsigned)lo;
        }
        __syncthreads();
        __threadfence();                        // release: make writes device-visible
        if (tid == 0) atomicAdd(&cnt[1], 1);
        return;
    }

    // ---------------- scan: block 0 (one wave, sync-free) ----------------
    if (blk == 0) {
        if (tid >= 64) return;
        int lane = tid;
        float a = 1.f / (1.f + __expf(-lvl_coef[0]));
        float g = 1.f / (1.f + __expf(-seas_coef[0]));
        float q = 1.f - a, gq = 1.f - g;

        for (int t = lane; t < T_S + 1; t += 64) w_all[t] = __expf(seas_params[t % T_S]);
        float lvl = x[0] / __expf(seas_params[0]);
        if (lane == 0) levels[0] = lvl;

        float wcur[3];
        #pragma unroll
        for (int i = 0; i < 3; ++i)
            wcur[i] = __expf(seas_params[(1 + 3 * lane + i) % T_S]);

        float f1 = q * q * q;
        float f2 = f1 * f1, f4 = f2 * f2, f8 = f4 * f4;
        float lnq = __logf(q);
        float P15 = __expf(3.f * (float)((lane & 15) + 1) * lnq);
        float P31 = __expf(3.f * (float)((lane & 31) + 1) * lnq);
        float pw3l = __expf(3.f * (float)lane * lnq);

        int nch = (T - 1 + T_S - 1) / T_S;
        int ngrp = (nch + 3) / 4;
        int j0 = 3 * lane;
        bool wr = (lane < 56);

        float xg[4][3], xh[4][3], x2[4][3];
        #pragma unroll
        for (int u = 0; u < 4; ++u)
            #pragma unroll
            for (int i = 0; i < 3; ++i) {
                xg[u][i] = x[min(1 + T_S * u + j0 + i, T - 1)];
                xh[u][i] = x[min(1 + T_S * (4 + u) + j0 + i, T - 1)];
            }

        float* pl = levels + 1 + j0;
        float* pw = w_all + 1 + T_S + j0;

        for (int grp = 0; grp < ngrp; ++grp) {
            #pragma unroll
            for (int u = 0; u < 4; ++u)
                #pragma unroll
                for (int i = 0; i < 3; ++i) {
                    int t = 1 + T_S * (4 * (grp + 2) + u) + j0 + i;
                    x2[u][i] = x[min(t, T - 1)];
                }

            #pragma unroll
            for (int u = 0; u < 4; ++u) {
                int c = 4 * grp + u;
                if (c >= nch) break;
                int len = (T - 1) - T_S * c; if (len > T_S) len = T_S;
                bool full = (len == T_S);

                float rr[3];
                #pragma unroll
                for (int i = 0; i < 3; ++i) rr[i] = a * xg[u][i] * __builtin_amdgcn_rcpf(wcur[i]);
                float S = fmaf(q, fmaf(q, rr[0], rr[1]), rr[2]);
                S = fmaf(f1, dppf<0x111, 0xf>(S), S);
                S = fmaf(f2, dppf<0x112, 0xf>(S), S);
                S = fmaf(f4, dppf<0x114, 0xf>(S), S);
                S = fmaf(f8, dppf<0x118, 0xf>(S), S);
                S = fmaf(P15, dppf<0x142, 0xa>(S), S);
                S = fmaf(P31, dppf<0x143, 0xc>(S), S);
                float E = dppf<0x138, 0xf>(S);

                float lv = fmaf(pw3l, lvl, E);
                float lev[3];
                #pragma unroll
                for (int i = 0; i < 3; ++i) { lv = fmaf(q, lv, rr[i]); lev[i] = lv; }
                { union { float f; int i; } uu; uu.i = __builtin_amdgcn_readlane(__builtin_bit_cast(int, lev[2]), 55); lvl = uu.f; }

                float wn[3];
                #pragma unroll
                for (int i = 0; i < 3; ++i)
                    wn[i] = fmaf(gq, wcur[i], g * xg[u][i] * __builtin_amdgcn_rcpf(lev[i]));

                if (full) {
                    if (wr) {
                        #pragma unroll
                        for (int i = 0; i < 3; ++i) { pl[i] = lev[i]; pw[i] = wn[i]; }
                    }
                } else {
                    #pragma unroll
                    for (int i = 0; i < 3; ++i)
                        if (j0 + i < len) { pl[i] = lev[i]; pw[i] = wn[i]; }
                }
                pl += T_S; pw += T_S;
                #pragma unroll
                for (int i = 0; i < 3; ++i) wcur[i] = wn[i];
            }
            #pragma unroll
            for (int u = 0; u < 4; ++u)
                #pragma unroll
                for (int i = 0; i < 3; ++i) { xg[u][i] = xh[u][i]; xh[u][i] = x2[u][i]; }

            // publish progress every 4 groups + at the end
            if ((grp & 3) == 3 || grp == ngrp - 1) {
                __threadfence();               // release: drain + make stores visible
                if (lane == 0) {
                    int v = T_S * 4 * (grp + 1); if (v > T - 1) v = T - 1;
                    atomicExch(&cnt[0], v);
                }
            }
        }
        return;
    }

    // ---------------- loss1: blocks 303+NB .. 303+NB+127 ----------------
    if (blk >= NPREP + 1 + NB) {
        int lb = blk - (NPREP + 1 + NB);
        if (tid == 0) {
            int cur;
            while ((cur = atomicAdd(&cnt[0], 0)) < T - 1) {
                int it = (T - 1 - cur) / 2400 + 1;
                for (int s = 0; s < it; ++s) __builtin_amdgcn_s_sleep(127);
            }
        }
        __syncthreads();
        __threadfence();                        // acquire: invalidate stale caches
        __shared__ float ls[CH + 2];
        __shared__ float red[256];
        int lo = lb * CH;
        int n = T - lo; if (n > CH + 2) n = CH + 2;
        for (int i = tid; i < n; i += 256) ls[i] = __logf(levels[lo + i]);
        __syncthreads();
        float s = 0.f;
        int dmax = (T - 2) - lo; if (dmax > CH) dmax = CH;
        for (int i = tid; i < dmax; i += 256) {
            float d = ls[i + 2] - 2.f * ls[i + 1] + ls[i];
            s = fmaf(d, d, s);
        }
        red[tid] = s;
        __syncthreads();
        for (int w = 128; w > 0; w >>= 1) {
            if (tid < w) red[tid] += red[tid + w];
            __syncthreads();
        }
        if (tid == 0) lpart[lb] = red[0];
        return;
    }

    // ---------------- gemm: blocks 303 .. 302+NB ----------------
    int gb = blk - (NPREP + 1);
    int lane = tid & 63, wv = tid >> 6;
    int lr = lane & 15, lq = lane >> 4;
    int n0 = gb * BM;
    int rw = wv * 32;

    if (tid == 0) {
        int target = n0 + 463; if (target > T - 1) target = T - 1;
        int cur;
        while ((cur = atomicAdd(&cnt[0], 0)) < target) {
            int it = (target - cur) / 2400 + 1;
            for (int s = 0; s < it; ++s) __builtin_amdgcn_s_sleep(127);
        }
        while (atomicAdd(&cnt[1], 0) < NPREP) __builtin_amdgcn_s_sleep(16);
    }
    __syncthreads();
    __threadfence();                            // acquire: invalidate stale caches

    // volatile: force vector load (scalar K$ is NOT invalidated by the fence)
    float C = __logf(*(volatile const float*)(levels + min(n0 + T_WIN, T - 1)));

    for (int i = tid; i < 512; i += 256) {
        int t = n0 + i;
        float v = (t < T) ? (__logf(x[t]) - __logf(w_all[t]) - C) : 0.f;
        Lsf[i] = v;
        Lbf0[i] = f2bf(v);
    }
    for (int i = tid; i < BM; i += 256) {
        int t = n0 + i + T_WIN;
        llv[i] = (t < T) ? (__logf(levels[t]) - C) : 0.f;
    }
    __syncthreads();
    for (int i = tid; i < 512; i += 256) Lbf1[i] = (i < 511) ? Lbf0[i + 1] : (short)0;
    __syncthreads();

    for (int u2 = tid; u2 < BM * T_OUT; u2 += 256) {
        int row = u2 / T_OUT, j = u2 - row * T_OUT;
        int nn = n0 + row;
        if (nn < N) lab[(size_t)nn * T_OUT + j] = Lsf[row + T_WIN + j] - llv[row];
    }

    const short* abase = ((lr & 1) ? Lbf1 : Lbf0) + rw + (lr & ~1);
    short8 af[11][2];
    #pragma unroll
    for (int kt = 0; kt < 11; ++kt) {
        #pragma unroll
        for (int mt = 0; mt < 2; ++mt) {
            const int* ip = (const int*)(abase + mt * 16 + kt * 32 + lq * 8);
            union { short8 s; int i[4]; } u;
            u.i[0] = ip[0]; u.i[1] = ip[1]; u.i[2] = ip[2]; u.i[3] = ip[3];
            af[kt][mt] = u.s;
        }
    }

    f32x4 zero4 = {0.f, 0.f, 0.f, 0.f};
    f32x4 acc2[2][3];
    #pragma unroll
    for (int mt = 0; mt < 2; ++mt)
        #pragma unroll
        for (int ct = 0; ct < 3; ++ct) acc2[mt][ct] = zero4;

    for (int c = 0; c < 6; ++c) {
        float b1v[4], csv[4];
        #pragma unroll
        for (int ct = 0; ct < 4; ++ct) {
            int col = c * 64 + ct * 16 + lr;
            b1v[ct] = (col < T_WIN) ? b1[col] : 0.f;
            csv[ct] = (col < T_WIN) ? cs[col] : 0.f;
        }

        f32x4 acc1[2][4];
        #pragma unroll
        for (int mt = 0; mt < 2; ++mt)
            #pragma unroll
            for (int ct = 0; ct < 4; ++ct) acc1[mt][ct] = zero4;

        const short* Wc1 = W1F + (size_t)c * 11 * 4 * 512;
        #pragma unroll
        for (int kt = 0; kt < 11; ++kt) {
            #pragma unroll
            for (int ct = 0; ct < 4; ++ct) {
                short8 bf = *(const short8*)&Wc1[((kt * 4 + ct) * 64 + lane) * 8];
                acc1[0][ct] = __builtin_amdgcn_mfma_f32_16x16x32_bf16(af[kt][0], bf, acc1[0][ct], 0, 0, 0);
                acc1[1][ct] = __builtin_amdgcn_mfma_f32_16x16x32_bf16(af[kt][1], bf, acc1[1][ct], 0, 0, 0);
            }
        }

        // epilogue -> hs (wave-local rows; no barrier needed)
        #pragma unroll
        for (int mt = 0; mt < 2; ++mt)
            #pragma unroll
            for (int ct = 0; ct < 4; ++ct)
                #pragma unroll
                for (int r = 0; r < 4; ++r) {
                    int row = rw + mt * 16 + lq * 4 + r;
                    float pre = acc1[mt][ct][r] + b1v[ct] - llv[row] * csv[ct];
                    float e = __expf(2.f * pre);
                    float h = 1.f - 2.f * __builtin_amdgcn_rcpf(e + 1.f);
                    hs[row * 72 + ct * 16 + lr] = f2bf(h);
                }

        #pragma unroll
        for (int kt2 = 0; kt2 < 2; ++kt2) {
            short8 a2[2];
            #pragma unroll
            for (int mt = 0; mt < 2; ++mt)
                a2[mt] = *(const short8*)&hs[(rw + mt * 16 + lr) * 72 + kt2 * 32 + lq * 8];
            #pragma unroll
            for (int ct2 = 0; ct2 < 3; ++ct2) {
                short8 bf2 = *(const short8*)&W2F[(((c * 2 + kt2) * 3 + ct2) * 64 + lane) * 8];
                acc2[0][ct2] = __builtin_amdgcn_mfma_f32_16x16x32_bf16(a2[0], bf2, acc2[0][ct2], 0, 0, 0);
                acc2[1][ct2] = __builtin_amdgcn_mfma_f32_16x16x32_bf16(a2[1], bf2, acc2[1][ct2], 0, 0, 0);
            }
        }
    }

    float b2v[3];
    #pragma unroll
    for (int ct2 = 0; ct2 < 3; ++ct2) b2v[ct2] = b2[ct2 * 16 + lr];
    #pragma unroll
    for (int mt = 0; mt < 2; ++mt)
        #pragma unroll
        for (int ct2 = 0; ct2 < 3; ++ct2)
            #pragma unroll
            for (int r = 0; r < 4; ++r) {
                int row = n0 + rw + mt * 16 + lq * 4 + r;
                if (row < N)
                    outp[(size_t)row * T_OUT + ct2 * 16 + lr] = acc2[mt][ct2][r] + b2v[ct2];
            }
}

__global__ __launch_bounds__(128) void loss2_kernel(
    const float* __restrict__ part, const int* __restrict__ lvp,
    float* __restrict__ out_loss, int T)
{
    __shared__ float red[128];
    red[threadIdx.x] = part[threadIdx.x];
    __syncthreads();
    for (int w = 64; w > 0; w >>= 1) {
        if (threadIdx.x < (unsigned)w) red[threadIdx.x] += red[threadIdx.x + w];
        __syncthreads();
    }
    if (threadIdx.x == 0) out_loss[0] = red[0] * (float)lvp[0] / (float)(T - 2);
}

extern "C" void kernel_launch(void* const* d_in, const int* in_sizes, int n_in,
                              void* d_out, int out_size, void* d_ws, size_t ws_size,
                              hipStream_t stream) {
    const float* x    = (const float*)d_in[0];
    const float* lvlc = (const float*)d_in[1];
    const float* seac = (const float*)d_in[2];
    const float* sp   = (const float*)d_in[3];
    const float* W1   = (const float*)d_in[4];
    const float* b1   = (const float*)d_in[5];
    const float* W2   = (const float*)d_in[6];
    const float* b2   = (const float*)d_in[7];
    const int*   lvp  = (const int*)d_in[10];

    int T = in_sizes[0];
    int N = T - T_WIN - T_OUT + 1;
    int NB = (N + BM - 1) / BM;

    short* W1F    = (short*)d_ws;                  // 264*512 shorts
    short* W2F    = W1F + 264 * 512;               // 36*512 shorts
    float* w_all  = (float*)(W2F + 36 * 512);      // T + 192
    float* levels = w_all + T + 192;               // T
    float* cs     = levels + T;                    // 352
    float* lpart  = cs + 352;                      // 128
    int*   cnt    = (int*)(lpart + 128);           // 2 counters (prog, prep_done)

    float* outp  = (float*)d_out;
    float* lab   = outp + (size_t)N * T_OUT;
    float* lossp = lab + (size_t)N * T_OUT;

    init_kernel<<<1, 1, 0, stream>>>(cnt);
    mega_kernel<<<NPREP + 1 + NB + 128, 256, 0, stream>>>(
        x, lvlc, seac, sp, W1, W2, b1, b2,
        w_all, levels, W1F, W2F, cs, lpart, outp, lab, cnt, T, N, NB);
    loss2_kernel<<<1, 128, 0, stream>>>(lpart, lvp, lossp, T);
}

// Round 13
// 284.630 us; speedup vs baseline: 1.4084x; 1.4084x over previous
//
#include <hip/hip_runtime.h>
#include <hip/hip_bf16.h>

#define T_WIN 336
#define T_OUT 48
#define T_S   168
#define BM    128
#define CH    782
#define NPREP 302

typedef __attribute__((ext_vector_type(8))) short short8;
typedef __attribute__((ext_vector_type(4))) float f32x4;

__device__ __forceinline__ short f2bf(float f) {
    union { float f; unsigned u; } v; v.f = f;
    unsigned r = v.u + 0x7FFFu + ((v.u >> 16) & 1u);
    return (short)(r >> 16);
}

template <int CTRL, int RMASK>
__device__ __forceinline__ float dppf(float v) {
    union { float f; int i; } in, out;
    in.f = v;
    out.i = __builtin_amdgcn_update_dpp(0, in.i, CTRL, RMASK, 0xf, true);
    return out.f;
}

// =============== fused: scan (block 0) + W1F/W2F prep + cs (blocks 1..302) ===============
__global__ __launch_bounds__(256, 1) void prep_scan_kernel(
    const float* __restrict__ x, const float* __restrict__ lvl_coef,
    const float* __restrict__ seas_coef, const float* __restrict__ seas_params,
    const float* __restrict__ W1, const float* __restrict__ W2,
    float* __restrict__ w_all, float* __restrict__ levels,
    short* __restrict__ W1F, short* __restrict__ W2F,
    float* __restrict__ cs, int T)
{
    int blk = blockIdx.x;
    int tid = threadIdx.x;

    if (blk >= 301) {              // ---- cs: colsum of W1 ----
        int k = (blk - 301) * 256 + tid;
        if (k < T_WIN) {
            float s = 0.f;
            for (int j = 0; j < T_WIN; ++j) s += W1[j * T_WIN + k];
            cs[k] = s;
        }
        return;
    }
    if (blk >= 265) {              // ---- W2F: [f=(c*2+kt2)*3+ct2][lane][j] ----
        int d = (blk - 265) * 256 + tid;
        int j2 = d & 3, lane = (d >> 2) & 63, f = d >> 8;
        int ct2 = f % 3, rest = f / 3;
        int kt2 = rest & 1, c = rest >> 1;
        int k = c * 64 + kt2 * 32 + (lane >> 4) * 8 + 2 * j2;
        int o = ct2 * 16 + (lane & 15);
        unsigned short lo = 0, hi = 0;
        if (k     < T_WIN) lo = (unsigned short)f2bf(W2[k * T_OUT + o]);
        if (k + 1 < T_WIN) hi = (unsigned short)f2bf(W2[(k + 1) * T_OUT + o]);
        ((unsigned*)W2F)[d] = ((unsigned)hi << 16) | (unsigned)lo;
        return;
    }
    if (blk >= 1) {                // ---- W1F: [c][kt][ct][lane][j] (chunk-contiguous) ----
        int d = (blk - 1) * 256 + tid;
        int j2 = d & 3, lane = (d >> 2) & 63, f = d >> 8;
        int ct = f & 3, rest = f >> 2;
        int kt = rest % 11, c = rest / 11;
        int k = kt * 32 + (lane >> 4) * 8 + 2 * j2;
        int col = c * 64 + ct * 16 + (lane & 15);
        unsigned short lo = 0, hi = 0;
        if (col < T_WIN) {
            if (k     < T_WIN) lo = (unsigned short)f2bf(W1[k * T_WIN + col]);
            if (k + 1 < T_WIN) hi = (unsigned short)f2bf(W1[(k + 1) * T_WIN + col]);
        }
        ((unsigned*)W1F)[d] = ((unsigned)hi << 16) | (unsigned)lo;
        return;
    }

    // ---- block 0: serial ES scan (one wave, DPP affine scan, sync-free) ----
    if (tid >= 64) return;
    int lane = tid;
    float a = 1.f / (1.f + __expf(-lvl_coef[0]));
    float g = 1.f / (1.f + __expf(-seas_coef[0]));
    float q = 1.f - a, gq = 1.f - g;

    for (int t = lane; t < T_S + 1; t += 64) w_all[t] = __expf(seas_params[t % T_S]);
    float lvl = x[0] / __expf(seas_params[0]);
    if (lane == 0) levels[0] = lvl;

    float wcur[3];
    #pragma unroll
    for (int i = 0; i < 3; ++i)
        wcur[i] = __expf(seas_params[(1 + 3 * lane + i) % T_S]);

    float f1 = q * q * q;
    float f2 = f1 * f1, f4 = f2 * f2, f8 = f4 * f4;
    float lnq = __logf(q);
    float P15 = __expf(3.f * (float)((lane & 15) + 1) * lnq);
    float P31 = __expf(3.f * (float)((lane & 31) + 1) * lnq);
    float pw3l = __expf(3.f * (float)lane * lnq);

    int nch = (T - 1 + T_S - 1) / T_S;
    int ngrp = (nch + 3) / 4;
    int j0 = 3 * lane;
    bool wr = (lane < 56);

    float xg[4][3], xh[4][3], x2[4][3];
    #pragma unroll
    for (int u = 0; u < 4; ++u)
        #pragma unroll
        for (int i = 0; i < 3; ++i) {
            xg[u][i] = x[min(1 + T_S * u + j0 + i, T - 1)];
            xh[u][i] = x[min(1 + T_S * (4 + u) + j0 + i, T - 1)];
        }

    float* pl = levels + 1 + j0;
    float* pw = w_all + 1 + T_S + j0;

    for (int grp = 0; grp < ngrp; ++grp) {
        #pragma unroll
        for (int u = 0; u < 4; ++u)
            #pragma unroll
            for (int i = 0; i < 3; ++i) {
                int t = 1 + T_S * (4 * (grp + 2) + u) + j0 + i;
                x2[u][i] = x[min(t, T - 1)];
            }

        #pragma unroll
        for (int u = 0; u < 4; ++u) {
            int c = 4 * grp + u;
            if (c >= nch) break;
            int len = (T - 1) - T_S * c; if (len > T_S) len = T_S;
            bool full = (len == T_S);

            float rr[3];
            #pragma unroll
            for (int i = 0; i < 3; ++i) rr[i] = a * xg[u][i] * __builtin_amdgcn_rcpf(wcur[i]);
            float S = fmaf(q, fmaf(q, rr[0], rr[1]), rr[2]);
            S = fmaf(f1, dppf<0x111, 0xf>(S), S);
            S = fmaf(f2, dppf<0x112, 0xf>(S), S);
            S = fmaf(f4, dppf<0x114, 0xf>(S), S);
            S = fmaf(f8, dppf<0x118, 0xf>(S), S);
            S = fmaf(P15, dppf<0x142, 0xa>(S), S);
            S = fmaf(P31, dppf<0x143, 0xc>(S), S);
            float E = dppf<0x138, 0xf>(S);

            float lv = fmaf(pw3l, lvl, E);
            float lev[3];
            #pragma unroll
            for (int i = 0; i < 3; ++i) { lv = fmaf(q, lv, rr[i]); lev[i] = lv; }
            { union { float f; int i; } uu; uu.i = __builtin_amdgcn_readlane(__builtin_bit_cast(int, lev[2]), 55); lvl = uu.f; }

            float wn[3];
            #pragma unroll
            for (int i = 0; i < 3; ++i)
                wn[i] = fmaf(gq, wcur[i], g * xg[u][i] * __builtin_amdgcn_rcpf(lev[i]));

            if (full) {
                if (wr) {
                    #pragma unroll
                    for (int i = 0; i < 3; ++i) { pl[i] = lev[i]; pw[i] = wn[i]; }
                }
            } else {
                #pragma unroll
                for (int i = 0; i < 3; ++i)
                    if (j0 + i < len) { pl[i] = lev[i]; pw[i] = wn[i]; }
            }
            pl += T_S; pw += T_S;
            #pragma unroll
            for (int i = 0; i < 3; ++i) wcur[i] = wn[i];
        }
        #pragma unroll
        for (int u = 0; u < 4; ++u)
            #pragma unroll
            for (int i = 0; i < 3; ++i) { xg[u][i] = xh[u][i]; xh[u][i] = x2[u][i]; }
    }
}

// ============ fused MLP (blocks [0,NB)) + loss1 partials (blocks [NB,NB+128)) ============
// gemm: MFMA GEMM1+GEMM2, block-centered bf16 (C = log level), labels fused.
// Round-13: per-chunk B1/B2 LDS staging via global_load_lds(16B). Round-10/11's plateau
// (~140us, all pipes idle) was every wave re-reading the whole 264KB W1F from L2
// (822 MB total). Staging once per block cuts that 4x and moves hot-loop B-reads to
// conflict-free ds_read_b128.
__global__ __launch_bounds__(256, 2) void gemm_kernel(
    const float* __restrict__ x, const float* __restrict__ w_all,
    const float* __restrict__ levels,
    const short* __restrict__ W1F, const short* __restrict__ W2F,
    const float* __restrict__ b1, const float* __restrict__ cs,
    const float* __restrict__ b2, float* __restrict__ outp,
    float* __restrict__ lab, float* __restrict__ lpart,
    int T, int N, int NB)
{
    __shared__ float Lsf[512];
    __shared__ __align__(16) short Lbf0[512];
    __shared__ __align__(16) short Lbf1[512];
    __shared__ float llv[BM];
    __shared__ __align__(16) short hs[BM * 72];       // 18432 B (loss1 aliases this)
    __shared__ __align__(16) short B1s[11 * 4 * 512]; // 45056 B
    __shared__ __align__(16) short B2s[6 * 512];      // 6144 B

    int blk = blockIdx.x;
    int tid = threadIdx.x;

    // ---------------- loss1 blocks ----------------
    if (blk >= NB) {
        float* ls  = (float*)hs;            // 3136 B needed
        float* red = (float*)(hs + 4096);   // 1024 B at +8192 B
        int lb = blk - NB;
        int lo = lb * CH;
        int n = T - lo; if (n > CH + 2) n = CH + 2;
        for (int i = tid; i < n; i += 256) ls[i] = __logf(levels[lo + i]);
        __syncthreads();
        float s = 0.f;
        int dmax = (T - 2) - lo; if (dmax > CH) dmax = CH;
        for (int i = tid; i < dmax; i += 256) {
            float d = ls[i + 2] - 2.f * ls[i + 1] + ls[i];
            s = fmaf(d, d, s);
        }
        red[tid] = s;
        __syncthreads();
        for (int w = 128; w > 0; w >>= 1) {
            if (tid < w) red[tid] += red[tid + w];
            __syncthreads();
        }
        if (tid == 0) lpart[lb] = red[0];
        return;
    }

    // ---------------- gemm blocks ----------------
    int lane = tid & 63, wv = tid >> 6;
    int lr = lane & 15, lq = lane >> 4;
    int n0 = blk * BM;
    int rw = wv * 32;

    float C = __logf(levels[min(n0 + T_WIN, T - 1)]);

    for (int i = tid; i < 512; i += 256) {
        int t = n0 + i;
        float v = (t < T) ? (__logf(x[t]) - __logf(w_all[t]) - C) : 0.f;
        Lsf[i] = v;
        Lbf0[i] = f2bf(v);
    }
    for (int i = tid; i < BM; i += 256) {
        int t = n0 + i + T_WIN;
        llv[i] = (t < T) ? (__logf(levels[t]) - C) : 0.f;
    }
    __syncthreads();
    for (int i = tid; i < 512; i += 256) Lbf1[i] = (i < 511) ? Lbf0[i + 1] : (short)0;
    __syncthreads();

    for (int u2 = tid; u2 < BM * T_OUT; u2 += 256) {
        int row = u2 / T_OUT, j = u2 - row * T_OUT;
        int nn = n0 + row;
        if (nn < N) lab[(size_t)nn * T_OUT + j] = Lsf[row + T_WIN + j] - llv[row];
    }

    // pack 22 A-fragments (parity arrays: 4B-aligned b32 reads)
    const short* abase = ((lr & 1) ? Lbf1 : Lbf0) + rw + (lr & ~1);
    short8 af[11][2];
    #pragma unroll
    for (int kt = 0; kt < 11; ++kt) {
        #pragma unroll
        for (int mt = 0; mt < 2; ++mt) {
            const int* ip = (const int*)(abase + mt * 16 + kt * 32 + lq * 8);
            union { short8 s; int i[4]; } u;
            u.i[0] = ip[0]; u.i[1] = ip[1]; u.i[2] = ip[2]; u.i[3] = ip[3];
            af[kt][mt] = u.s;
        }
    }

    f32x4 zero4 = {0.f, 0.f, 0.f, 0.f};
    f32x4 acc2[2][3];
    #pragma unroll
    for (int mt = 0; mt < 2; ++mt)
        #pragma unroll
        for (int ct = 0; ct < 3; ++ct) acc2[mt][ct] = zero4;

    for (int c = 0; c < 6; ++c) {
        __syncthreads();   // previous chunk's B1s/B2s/hs consumers done

        // stage this chunk's B1 slice (44 x 1KB) + B2 slice (6 x 1KB): m97 pattern
        const char* g1 = (const char*)(W1F + (size_t)c * 11 * 4 * 512);
        for (int seg = wv; seg < 44; seg += 4) {
            __builtin_amdgcn_global_load_lds(
                (const __attribute__((address_space(1))) unsigned int*)(g1 + seg * 1024 + lane * 16),
                (__attribute__((address_space(3))) unsigned int*)((char*)B1s + seg * 1024),
                16, 0, 0);
        }
        const char* g2 = (const char*)(W2F + (size_t)c * 6 * 512);
        for (int seg = wv; seg < 6; seg += 4) {
            __builtin_amdgcn_global_load_lds(
                (const __attribute__((address_space(1))) unsigned int*)(g2 + seg * 1024 + lane * 16),
                (__attribute__((address_space(3))) unsigned int*)((char*)B2s + seg * 1024),
                16, 0, 0);
        }
        // per-col fold constants (overlap with staging)
        float b1v[4], csv[4];
        #pragma unroll
        for (int ct = 0; ct < 4; ++ct) {
            int col = c * 64 + ct * 16 + lr;
            b1v[ct] = (col < T_WIN) ? b1[col] : 0.f;
            csv[ct] = (col < T_WIN) ? cs[col] : 0.f;
        }
        __syncthreads();   // staging visible (vmcnt drained)

        // --- GEMM1: B-frags from LDS (conflict-free b128) ---
        f32x4 acc1[2][4];
        #pragma unroll
        for (int mt = 0; mt < 2; ++mt)
            #pragma unroll
            for (int ct = 0; ct < 4; ++ct) acc1[mt][ct] = zero4;

        #pragma unroll
        for (int kt = 0; kt < 11; ++kt) {
            #pragma unroll
            for (int ct = 0; ct < 4; ++ct) {
                short8 bf = *(const short8*)&B1s[((kt * 4 + ct) * 64 + lane) * 8];
                acc1[0][ct] = __builtin_amdgcn_mfma_f32_16x16x32_bf16(af[kt][0], bf, acc1[0][ct], 0, 0, 0);
                acc1[1][ct] = __builtin_amdgcn_mfma_f32_16x16x32_bf16(af[kt][1], bf, acc1[1][ct], 0, 0, 0);
            }
        }

        // epilogue -> hs (wave-local rows; no extra barrier)
        #pragma unroll
        for (int mt = 0; mt < 2; ++mt)
            #pragma unroll
            for (int ct = 0; ct < 4; ++ct)
                #pragma unroll
                for (int r = 0; r < 4; ++r) {
                    int row = rw + mt * 16 + lq * 4 + r;
                    float pre = acc1[mt][ct][r] + b1v[ct] - llv[row] * csv[ct];
                    float e = __expf(2.f * pre);
                    float h = 1.f - 2.f * __builtin_amdgcn_rcpf(e + 1.f);
                    hs[row * 72 + ct * 16 + lr] = f2bf(h);
                }

        // --- GEMM2: A from own rows of hs, B from B2s ---
        #pragma unroll
        for (int kt2 = 0; kt2 < 2; ++kt2) {
            short8 a2[2];
            #pragma unroll
            for (int mt = 0; mt < 2; ++mt)
                a2[mt] = *(const short8*)&hs[(rw + mt * 16 + lr) * 72 + kt2 * 32 + lq * 8];
            #pragma unroll
            for (int ct2 = 0; ct2 < 3; ++ct2) {
                short8 bf2 = *(const short8*)&B2s[((kt2 * 3 + ct2) * 64 + lane) * 8];
                acc2[0][ct2] = __builtin_amdgcn_mfma_f32_16x16x32_bf16(a2[0], bf2, acc2[0][ct2], 0, 0, 0);
                acc2[1][ct2] = __builtin_amdgcn_mfma_f32_16x16x32_bf16(a2[1], bf2, acc2[1][ct2], 0, 0, 0);
            }
        }
    }

    float b2v[3];
    #pragma unroll
    for (int ct2 = 0; ct2 < 3; ++ct2) b2v[ct2] = b2[ct2 * 16 + lr];
    #pragma unroll
    for (int mt = 0; mt < 2; ++mt)
        #pragma unroll
        for (int ct2 = 0; ct2 < 3; ++ct2)
            #pragma unroll
            for (int r = 0; r < 4; ++r) {
                int row = n0 + rw + mt * 16 + lq * 4 + r;
                if (row < N)
                    outp[(size_t)row * T_OUT + ct2 * 16 + lr] = acc2[mt][ct2][r] + b2v[ct2];
            }
}

__global__ __launch_bounds__(128) void loss2_kernel(
    const float* __restrict__ part, const int* __restrict__ lvp,
    float* __restrict__ out_loss, int T)
{
    __shared__ float red[128];
    red[threadIdx.x] = part[threadIdx.x];
    __syncthreads();
    for (int w = 64; w > 0; w >>= 1) {
        if (threadIdx.x < (unsigned)w) red[threadIdx.x] += red[threadIdx.x + w];
        __syncthreads();
    }
    if (threadIdx.x == 0) out_loss[0] = red[0] * (float)lvp[0] / (float)(T - 2);
}

extern "C" void kernel_launch(void* const* d_in, const int* in_sizes, int n_in,
                              void* d_out, int out_size, void* d_ws, size_t ws_size,
                              hipStream_t stream) {
    const float* x    = (const float*)d_in[0];
    const float* lvlc = (const float*)d_in[1];
    const float* seac = (const float*)d_in[2];
    const float* sp   = (const float*)d_in[3];
    const float* W1   = (const float*)d_in[4];
    const float* b1   = (const float*)d_in[5];
    const float* W2   = (const float*)d_in[6];
    const float* b2   = (const float*)d_in[7];
    const int*   lvp  = (const int*)d_in[10];

    int T = in_sizes[0];
    int N = T - T_WIN - T_OUT + 1;
    int NB = (N + BM - 1) / BM;

    short* W1F    = (short*)d_ws;                  // 264*512 shorts
    short* W2F    = W1F + 264 * 512;               // 36*512 shorts
    float* w_all  = (float*)(W2F + 36 * 512);      // T + 192
    float* levels = w_all + T + 192;               // T
    float* cs     = levels + T;                    // 352
    float* lpart  = cs + 352;                      // 128

    float* outp  = (float*)d_out;
    float* lab   = outp + (size_t)N * T_OUT;
    float* lossp = lab + (size_t)N * T_OUT;

    prep_scan_kernel<<<303, 256, 0, stream>>>(x, lvlc, seac, sp, W1, W2,
                                              w_all, levels, W1F, W2F, cs, T);
    gemm_kernel<<<NB + 128, 256, 0, stream>>>(x, w_all, levels, W1F, W2F,
                                              b1, cs, b2, outp, lab, lpart, T, N, NB);
    loss2_kernel<<<1, 128, 0, stream>>>(lpart, lvp, lossp, T);
}

// Round 14
// 232.588 us; speedup vs baseline: 1.7236x; 1.2238x over previous
//
#include <hip/hip_runtime.h>
#include <hip/hip_bf16.h>

#define T_WIN 336
#define T_OUT 48
#define T_S   168
#define BM    128
#define CH    782

typedef __attribute__((ext_vector_type(8))) short short8;
typedef __attribute__((ext_vector_type(4))) float f32x4;

__device__ __forceinline__ short f2bf(float f) {
    union { float f; unsigned u; } v; v.f = f;
    unsigned r = v.u + 0x7FFFu + ((v.u >> 16) & 1u);
    return (short)(r >> 16);
}

template <int CTRL, int RMASK>
__device__ __forceinline__ float dppf(float v) {
    union { float f; int i; } in, out;
    in.f = v;
    out.i = __builtin_amdgcn_update_dpp(0, in.i, CTRL, RMASK, 0xf, true);
    return out.f;
}

// =============== fused: scan (block 0) + W1F/W2F prep + cs (blocks 1..302) ===============
__global__ __launch_bounds__(256, 1) void prep_scan_kernel(
    const float* __restrict__ x, const float* __restrict__ lvl_coef,
    const float* __restrict__ seas_coef, const float* __restrict__ seas_params,
    const float* __restrict__ W1, const float* __restrict__ W2,
    float* __restrict__ w_all, float* __restrict__ levels,
    short* __restrict__ W1F, short* __restrict__ W2F,
    float* __restrict__ cs, int T)
{
    int blk = blockIdx.x;
    int tid = threadIdx.x;

    if (blk >= 301) {              // ---- cs: colsum of W1 ----
        int k = (blk - 301) * 256 + tid;
        if (k < T_WIN) {
            float s = 0.f;
            for (int j = 0; j < T_WIN; ++j) s += W1[j * T_WIN + k];
            cs[k] = s;
        }
        return;
    }
    if (blk >= 265) {              // ---- W2F: [f=(c*2+kt2)*3+ct2][lane][j] ----
        int d = (blk - 265) * 256 + tid;
        int j2 = d & 3, lane = (d >> 2) & 63, f = d >> 8;
        int ct2 = f % 3, rest = f / 3;
        int kt2 = rest & 1, c = rest >> 1;
        int k = c * 64 + kt2 * 32 + (lane >> 4) * 8 + 2 * j2;
        int o = ct2 * 16 + (lane & 15);
        unsigned short lo = 0, hi = 0;
        if (k     < T_WIN) lo = (unsigned short)f2bf(W2[k * T_OUT + o]);
        if (k + 1 < T_WIN) hi = (unsigned short)f2bf(W2[(k + 1) * T_OUT + o]);
        ((unsigned*)W2F)[d] = ((unsigned)hi << 16) | (unsigned)lo;
        return;
    }
    if (blk >= 1) {                // ---- W1F: [c][kt][ct][lane][j] (chunk-contiguous) ----
        int d = (blk - 1) * 256 + tid;
        int j2 = d & 3, lane = (d >> 2) & 63, f = d >> 8;
        int ct = f & 3, rest = f >> 2;
        int kt = rest % 11, c = rest / 11;
        int k = kt * 32 + (lane >> 4) * 8 + 2 * j2;
        int col = c * 64 + ct * 16 + (lane & 15);
        unsigned short lo = 0, hi = 0;
        if (col < T_WIN) {
            if (k     < T_WIN) lo = (unsigned short)f2bf(W1[k * T_WIN + col]);
            if (k + 1 < T_WIN) hi = (unsigned short)f2bf(W1[(k + 1) * T_WIN + col]);
        }
        ((unsigned*)W1F)[d] = ((unsigned)hi << 16) | (unsigned)lo;
        return;
    }

    // ---- block 0: serial ES scan (one wave, DPP affine scan, sync-free) ----
    // Round-14 diet: 148 guard-free groups (chunks 0..591) with UNCONDITIONAL 64-lane
    // stores (lanes 56-63 write garbage into [t0+168,t0+191], deterministically
    // overwritten by chunk c+1's lanes 0-7; garbage stays finite: positive recurrence),
    // tail chunks 592..595 peeled with guards. Kills len math + exec-mask churn/chunk.
    if (tid >= 64) return;
    int lane = tid;
    float a = 1.f / (1.f + __expf(-lvl_coef[0]));
    float g = 1.f / (1.f + __expf(-seas_coef[0]));
    float q = 1.f - a, gq = 1.f - g;

    for (int t = lane; t < T_S + 1; t += 64) w_all[t] = __expf(seas_params[t % T_S]);
    float lvl = x[0] / __expf(seas_params[0]);
    if (lane == 0) levels[0] = lvl;

    float wcur[3];
    #pragma unroll
    for (int i = 0; i < 3; ++i)
        wcur[i] = __expf(seas_params[(1 + 3 * lane + i) % T_S]);

    float f1 = q * q * q;
    float f2 = f1 * f1, f4 = f2 * f2, f8 = f4 * f4;
    float lnq = __logf(q);
    float P15 = __expf(3.f * (float)((lane & 15) + 1) * lnq);
    float P31 = __expf(3.f * (float)((lane & 31) + 1) * lnq);
    float pw3l = __expf(3.f * (float)lane * lnq);

    int j0 = 3 * lane;

    // one chunk's serial math; updates wcur & lvl, returns lev
    auto do_chunk = [&](const float* xvv, float* lev) {
        float rr[3];
        #pragma unroll
        for (int i = 0; i < 3; ++i) rr[i] = a * xvv[i] * __builtin_amdgcn_rcpf(wcur[i]);
        float S = fmaf(q, fmaf(q, rr[0], rr[1]), rr[2]);
        S = fmaf(f1, dppf<0x111, 0xf>(S), S);   // row_shr:1
        S = fmaf(f2, dppf<0x112, 0xf>(S), S);   // row_shr:2
        S = fmaf(f4, dppf<0x114, 0xf>(S), S);   // row_shr:4
        S = fmaf(f8, dppf<0x118, 0xf>(S), S);   // row_shr:8
        S = fmaf(P15, dppf<0x142, 0xa>(S), S);  // row_bcast:15 -> rows 1,3
        S = fmaf(P31, dppf<0x143, 0xc>(S), S);  // row_bcast:31 -> rows 2,3
        float E = dppf<0x138, 0xf>(S);          // wave_shr:1 (exclusive)
        float lv = fmaf(pw3l, lvl, E);
        #pragma unroll
        for (int i = 0; i < 3; ++i) { lv = fmaf(q, lv, rr[i]); lev[i] = lv; }
        { union { float f; int i; } uu; uu.i = __builtin_amdgcn_readlane(__builtin_bit_cast(int, lev[2]), 55); lvl = uu.f; }
        #pragma unroll
        for (int i = 0; i < 3; ++i)
            wcur[i] = fmaf(gq, wcur[i], g * xvv[i] * __builtin_amdgcn_rcpf(lev[i]));
    };

    // depth-2 group prefetch pipeline
    float xg[4][3], xh[4][3], x2[4][3];
    #pragma unroll
    for (int u = 0; u < 4; ++u)
        #pragma unroll
        for (int i = 0; i < 3; ++i) {
            xg[u][i] = x[1 + T_S * u + j0 + i];            // chunks 0..7: always in-range
            xh[u][i] = x[1 + T_S * (4 + u) + j0 + i];
        }

    const float* px = x + 1 + 8 * T_S + j0;   // group 2 base
    float* pl = levels + 1 + j0;
    float* pw = w_all + 1 + T_S + j0;

    for (int grp = 0; grp < 148; ++grp) {
        // prefetch group grp+2
        if (grp < 146) {
            #pragma unroll
            for (int u = 0; u < 4; ++u)
                #pragma unroll
                for (int i = 0; i < 3; ++i)
                    x2[u][i] = px[u * T_S + i];
        } else {
            #pragma unroll
            for (int u = 0; u < 4; ++u)
                #pragma unroll
                for (int i = 0; i < 3; ++i) {
                    int t = 1 + T_S * (4 * (grp + 2) + u) + j0 + i;
                    x2[u][i] = x[min(t, T - 1)];
                }
        }
        px += 4 * T_S;

        #pragma unroll
        for (int u = 0; u < 4; ++u) {
            float lev[3];
            do_chunk(xg[u], lev);
            // unconditional stores (compiler merges to dwordx3)
            #pragma unroll
            for (int i = 0; i < 3; ++i) {
                pl[u * T_S + i] = lev[i];
                pw[u * T_S + i] = wcur[i];
            }
        }
        pl += 4 * T_S; pw += 4 * T_S;
        #pragma unroll
        for (int u = 0; u < 4; ++u)
            #pragma unroll
            for (int i = 0; i < 3; ++i) { xg[u][i] = xh[u][i]; xh[u][i] = x2[u][i]; }
    }

    // tail: chunks 592..595 (xg holds group 148), guarded stores
    #pragma unroll
    for (int u = 0; u < 4; ++u) {
        int c = 592 + u;
        if (c * T_S >= T - 1) break;
        int len = (T - 1) - T_S * c; if (len > T_S) len = T_S;
        float lev[3];
        do_chunk(xg[u], lev);
        #pragma unroll
        for (int i = 0; i < 3; ++i) {
            if (j0 + i < len) {
                pl[u * T_S + i] = lev[i];
                pw[u * T_S + i] = wcur[i];
            }
        }
    }
}

// ============ fused MLP (blocks [0,NB)) + loss1 partials (blocks [NB,NB+128)) ============
// gemm: MFMA GEMM1+GEMM2, block-centered bf16, labels fused, per-chunk LDS staging.
// Round-14: '#pragma unroll 1' on the chunk loop — unrolled x6 the body is ~48KB of code
// (> 32KB I$); rolled it is ~8KB. Tests the I$-thrash theory for the ~130us latency wall.
__global__ __launch_bounds__(256, 2) void gemm_kernel(
    const float* __restrict__ x, const float* __restrict__ w_all,
    const float* __restrict__ levels,
    const short* __restrict__ W1F, const short* __restrict__ W2F,
    const float* __restrict__ b1, const float* __restrict__ cs,
    const float* __restrict__ b2, float* __restrict__ outp,
    float* __restrict__ lab, float* __restrict__ lpart,
    int T, int N, int NB)
{
    __shared__ float Lsf[512];
    __shared__ __align__(16) short Lbf0[512];
    __shared__ __align__(16) short Lbf1[512];
    __shared__ float llv[BM];
    __shared__ __align__(16) short hs[BM * 72];       // 18432 B (loss1 aliases this)
    __shared__ __align__(16) short B1s[11 * 4 * 512]; // 45056 B
    __shared__ __align__(16) short B2s[6 * 512];      // 6144 B

    int blk = blockIdx.x;
    int tid = threadIdx.x;

    // ---------------- loss1 blocks ----------------
    if (blk >= NB) {
        float* ls  = (float*)hs;
        float* red = (float*)(hs + 4096);
        int lb = blk - NB;
        int lo = lb * CH;
        int n = T - lo; if (n > CH + 2) n = CH + 2;
        for (int i = tid; i < n; i += 256) ls[i] = __logf(levels[lo + i]);
        __syncthreads();
        float s = 0.f;
        int dmax = (T - 2) - lo; if (dmax > CH) dmax = CH;
        for (int i = tid; i < dmax; i += 256) {
            float d = ls[i + 2] - 2.f * ls[i + 1] + ls[i];
            s = fmaf(d, d, s);
        }
        red[tid] = s;
        __syncthreads();
        for (int w = 128; w > 0; w >>= 1) {
            if (tid < w) red[tid] += red[tid + w];
            __syncthreads();
        }
        if (tid == 0) lpart[lb] = red[0];
        return;
    }

    // ---------------- gemm blocks ----------------
    int lane = tid & 63, wv = tid >> 6;
    int lr = lane & 15, lq = lane >> 4;
    int n0 = blk * BM;
    int rw = wv * 32;

    float C = __logf(levels[min(n0 + T_WIN, T - 1)]);

    for (int i = tid; i < 512; i += 256) {
        int t = n0 + i;
        float v = (t < T) ? (__logf(x[t]) - __logf(w_all[t]) - C) : 0.f;
        Lsf[i] = v;
        Lbf0[i] = f2bf(v);
    }
    for (int i = tid; i < BM; i += 256) {
        int t = n0 + i + T_WIN;
        llv[i] = (t < T) ? (__logf(levels[t]) - C) : 0.f;
    }
    __syncthreads();
    for (int i = tid; i < 512; i += 256) Lbf1[i] = (i < 511) ? Lbf0[i + 1] : (short)0;
    __syncthreads();

    for (int u2 = tid; u2 < BM * T_OUT; u2 += 256) {
        int row = u2 / T_OUT, j = u2 - row * T_OUT;
        int nn = n0 + row;
        if (nn < N) lab[(size_t)nn * T_OUT + j] = Lsf[row + T_WIN + j] - llv[row];
    }

    // pack 22 A-fragments (parity arrays: 4B-aligned b32 reads)
    const short* abase = ((lr & 1) ? Lbf1 : Lbf0) + rw + (lr & ~1);
    short8 af[11][2];
    #pragma unroll
    for (int kt = 0; kt < 11; ++kt) {
        #pragma unroll
        for (int mt = 0; mt < 2; ++mt) {
            const int* ip = (const int*)(abase + mt * 16 + kt * 32 + lq * 8);
            union { short8 s; int i[4]; } u;
            u.i[0] = ip[0]; u.i[1] = ip[1]; u.i[2] = ip[2]; u.i[3] = ip[3];
            af[kt][mt] = u.s;
        }
    }

    f32x4 zero4 = {0.f, 0.f, 0.f, 0.f};
    f32x4 acc2[2][3];
    #pragma unroll
    for (int mt = 0; mt < 2; ++mt)
        #pragma unroll
        for (int ct = 0; ct < 3; ++ct) acc2[mt][ct] = zero4;

    #pragma unroll 1
    for (int c = 0; c < 6; ++c) {
        __syncthreads();   // previous chunk's B1s/B2s/hs consumers done

        const char* g1 = (const char*)(W1F + (size_t)c * 11 * 4 * 512);
        for (int seg = wv; seg < 44; seg += 4) {
            __builtin_amdgcn_global_load_lds(
                (const __attribute__((address_space(1))) unsigned int*)(g1 + seg * 1024 + lane * 16),
                (__attribute__((address_space(3))) unsigned int*)((char*)B1s + seg * 1024),
                16, 0, 0);
        }
        const char* g2 = (const char*)(W2F + (size_t)c * 6 * 512);
        for (int seg = wv; seg < 6; seg += 4) {
            __builtin_amdgcn_global_load_lds(
                (const __attribute__((address_space(1))) unsigned int*)(g2 + seg * 1024 + lane * 16),
                (__attribute__((address_space(3))) unsigned int*)((char*)B2s + seg * 1024),
                16, 0, 0);
        }
        float b1v[4], csv[4];
        #pragma unroll
        for (int ct = 0; ct < 4; ++ct) {
            int col = c * 64 + ct * 16 + lr;
            b1v[ct] = (col < T_WIN) ? b1[col] : 0.f;
            csv[ct] = (col < T_WIN) ? cs[col] : 0.f;
        }
        __syncthreads();   // staging visible (vmcnt drained)

        f32x4 acc1[2][4];
        #pragma unroll
        for (int mt = 0; mt < 2; ++mt)
            #pragma unroll
            for (int ct = 0; ct < 4; ++ct) acc1[mt][ct] = zero4;

        #pragma unroll
        for (int kt = 0; kt < 11; ++kt) {
            #pragma unroll
            for (int ct = 0; ct < 4; ++ct) {
                short8 bf = *(const short8*)&B1s[((kt * 4 + ct) * 64 + lane) * 8];
                acc1[0][ct] = __builtin_amdgcn_mfma_f32_16x16x32_bf16(af[kt][0], bf, acc1[0][ct], 0, 0, 0);
                acc1[1][ct] = __builtin_amdgcn_mfma_f32_16x16x32_bf16(af[kt][1], bf, acc1[1][ct], 0, 0, 0);
            }
        }

        // epilogue -> hs (wave-local rows; no extra barrier)
        #pragma unroll
        for (int mt = 0; mt < 2; ++mt)
            #pragma unroll
            for (int ct = 0; ct < 4; ++ct)
                #pragma unroll
                for (int r = 0; r < 4; ++r) {
                    int row = rw + mt * 16 + lq * 4 + r;
                    float pre = acc1[mt][ct][r] + b1v[ct] - llv[row] * csv[ct];
                    float e = __expf(2.f * pre);
                    float h = 1.f - 2.f * __builtin_amdgcn_rcpf(e + 1.f);
                    hs[row * 72 + ct * 16 + lr] = f2bf(h);
                }

        #pragma unroll
        for (int kt2 = 0; kt2 < 2; ++kt2) {
            short8 a2[2];
            #pragma unroll
            for (int mt = 0; mt < 2; ++mt)
                a2[mt] = *(const short8*)&hs[(rw + mt * 16 + lr) * 72 + kt2 * 32 + lq * 8];
            #pragma unroll
            for (int ct2 = 0; ct2 < 3; ++ct2) {
                short8 bf2 = *(const short8*)&B2s[((kt2 * 3 + ct2) * 64 + lane) * 8];
                acc2[0][ct2] = __builtin_amdgcn_mfma_f32_16x16x32_bf16(a2[0], bf2, acc2[0][ct2], 0, 0, 0);
                acc2[1][ct2] = __builtin_amdgcn_mfma_f32_16x16x32_bf16(a2[1], bf2, acc2[1][ct2], 0, 0, 0);
            }
        }
    }

    float b2v[3];
    #pragma unroll
    for (int ct2 = 0; ct2 < 3; ++ct2) b2v[ct2] = b2[ct2 * 16 + lr];
    #pragma unroll
    for (int mt = 0; mt < 2; ++mt)
        #pragma unroll
        for (int ct2 = 0; ct2 < 3; ++ct2)
            #pragma unroll
            for (int r = 0; r < 4; ++r) {
                int row = n0 + rw + mt * 16 + lq * 4 + r;
                if (row < N)
                    outp[(size_t)row * T_OUT + ct2 * 16 + lr] = acc2[mt][ct2][r] + b2v[ct2];
            }
}

__global__ __launch_bounds__(128) void loss2_kernel(
    const float* __restrict__ part, const int* __restrict__ lvp,
    float* __restrict__ out_loss, int T)
{
    __shared__ float red[128];
    red[threadIdx.x] = part[threadIdx.x];
    __syncthreads();
    for (int w = 64; w > 0; w >>= 1) {
        if (threadIdx.x < (unsigned)w) red[threadIdx.x] += red[threadIdx.x + w];
        __syncthreads();
    }
    if (threadIdx.x == 0) out_loss[0] = red[0] * (float)lvp[0] / (float)(T - 2);
}

extern "C" void kernel_launch(void* const* d_in, const int* in_sizes, int n_in,
                              void* d_out, int out_size, void* d_ws, size_t ws_size,
                              hipStream_t stream) {
    const float* x    = (const float*)d_in[0];
    const float* lvlc = (const float*)d_in[1];
    const float* seac = (const float*)d_in[2];
    const float* sp   = (const float*)d_in[3];
    const float* W1   = (const float*)d_in[4];
    const float* b1   = (const float*)d_in[5];
    const float* W2   = (const float*)d_in[6];
    const float* b2   = (const float*)d_in[7];
    const int*   lvp  = (const int*)d_in[10];

    int T = in_sizes[0];
    int N = T - T_WIN - T_OUT + 1;
    int NB = (N + BM - 1) / BM;

    short* W1F    = (short*)d_ws;                  // 264*512 shorts
    short* W2F    = W1F + 264 * 512;               // 36*512 shorts
    float* w_all  = (float*)(W2F + 36 * 512);      // T + 192
    float* levels = w_all + T + 192;               // T
    float* cs     = levels + T;                    // 352
    float* lpart  = cs + 352;                      // 128

    float* outp  = (float*)d_out;
    float* lab   = outp + (size_t)N * T_OUT;
    float* lossp = lab + (size_t)N * T_OUT;

    prep_scan_kernel<<<303, 256, 0, stream>>>(x, lvlc, seac, sp, W1, W2,
                                              w_all, levels, W1F, W2F, cs, T);
    gemm_kernel<<<NB + 128, 256, 0, stream>>>(x, w_all, levels, W1F, W2F,
                                              b1, cs, b2, outp, lab, lpart, T, N, NB);
    loss2_kernel<<<1, 128, 0, stream>>>(lpart, lvp, lossp, T);
}